// Round 7
// baseline (49.247 us; speedup 1.0000x reference)
//
#include <hip/hip_runtime.h>
#include <hip/hip_bf16.h>

// QuantizedLinear: out[t][o] = scale[o]*(sum_k x[t][k]*q[o][k] - zp[o]*sum_k x[t][k]) + bias[o]
// T=8, K=4096, OUT=11008. Weights int32 (int8-valued): 180.4 MB unique.
//
// R7 theory: R1/R2/R5/R6 (43-49us) all pushed ~352 MB of L1-miss traffic
// (q 176 MB unique + x 176 MB instr-traffic whose 64-128 KB/block footprint
// streams through the 32 KB L1) at a common ~8 TB/s delivery ceiling.
// Fix: block = 4 waves sharing ONE Kc=512 k-window -> x-footprint 16 KB
// (L1-resident; wave 0 misses, waves 1-3 hit). q read exactly once.
// Miss traffic ~ 176 + 44 + atomics ~= 240 MB -> predict 28-33 us.
//
// Structure: grid = 344 ch-groups x 8 k-chunks = 2752 blocks, 256 thr.
//   cg = bid>>3 (32 channels), chunk = bid&7 (512 k). Wave w: channels
//   cg*32 + w*8 .. +7, all 8 tokens, the block's k-window. 2 iters of 256 k:
//   8 float4 x-loads + 8 int4 q-loads per iter (1024 B/instr, coalesced).
//   acc[64] (8t x 8c); R2's verified 6-stage butterfly -> lane l holds
//   output j=l (t=l>>3, c=l&7). Combine across chunks: fp32 atomicAdd into
//   out (zeroed via hipMemsetAsync); chunk 0 adds bias; zp per-chunk (linear).
//   No LDS, no __syncthreads, no d_ws.

constexpr int K_IN   = 4096;
constexpr int N_OUT  = 11008;
constexpr int KC     = 512;          // k-window per block
constexpr int NCHUNK = K_IN / KC;    // 8

__global__ __launch_bounds__(256) void qlin_kernel(
    const float* __restrict__ x,
    const int*   __restrict__ q,
    const float* __restrict__ scale,
    const int*   __restrict__ zp,
    const float* __restrict__ bias,
    float*       __restrict__ out)
{
    const int tid   = threadIdx.x;
    const int lane  = tid & 63;
    const int w     = tid >> 6;            // 0..3: channel subgroup
    const int cg    = blockIdx.x >> 3;     // 0..343
    const int chunk = blockIdx.x & (NCHUNK - 1);
    const int obase = cg * 32 + w * 8;
    const int kbase = chunk * KC;

    float acc[64];
    #pragma unroll
    for (int i = 0; i < 64; ++i) acc[i] = 0.0f;
    float xs[8];
    #pragma unroll
    for (int t = 0; t < 8; ++t) xs[t] = 0.0f;

    #pragma unroll
    for (int it = 0; it < KC / 256; ++it) {
        const int k0 = kbase + it * 256 + lane * 4;

        float4 xv[8];
        #pragma unroll
        for (int t = 0; t < 8; ++t)
            xv[t] = *reinterpret_cast<const float4*>(&x[t * K_IN + k0]);

        int4 qv[8];
        #pragma unroll
        for (int c = 0; c < 8; ++c)
            qv[c] = *reinterpret_cast<const int4*>(&q[(obase + c) * K_IN + k0]);

        #pragma unroll
        for (int c = 0; c < 8; ++c) {
            const float q0 = (float)qv[c].x;
            const float q1 = (float)qv[c].y;
            const float q2 = (float)qv[c].z;
            const float q3 = (float)qv[c].w;
            #pragma unroll
            for (int t = 0; t < 8; ++t) {
                acc[t * 8 + c] += xv[t].x * q0 + xv[t].y * q1
                                + xv[t].z * q2 + xv[t].w * q3;
            }
        }
        #pragma unroll
        for (int t = 0; t < 8; ++t)
            xs[t] += xv[t].x + xv[t].y + xv[t].z + xv[t].w;
    }

    // R2's verified 6-stage halving butterfly: 64 partials x 64 lanes ->
    // lane l holds fully-reduced value j=l (t=l>>3, c=l&7).
    #pragma unroll
    for (int s = 0; s < 6; ++s) {
        const int m    = 32 >> s;
        const int half = 32 >> s;
        const bool hi  = (lane & m) != 0;
        #pragma unroll
        for (int i = 0; i < half; ++i) {
            const float a = acc[i];
            const float b = acc[i + half];
            const float send = hi ? a : b;
            const float recv = __shfl_xor(send, m, 64);
            acc[i] = (hi ? b : a) + recv;
        }
    }

    // Per-token x sums over this block's k-window (all lanes get all 8).
    #pragma unroll
    for (int m = 1; m <= 32; m <<= 1) {
        #pragma unroll
        for (int t = 0; t < 8; ++t)
            xs[t] += __shfl_xor(xs[t], m, 64);
    }

    const int t = lane >> 3;
    const int c = lane & 7;
    const int o = obase + c;
    float val = scale[o] * (acc[0] - (float)zp[o] * xs[t]);
    if (chunk == 0) val += bias[o];
    atomicAdd(&out[t * N_OUT + o], val);
}

extern "C" void kernel_launch(void* const* d_in, const int* in_sizes, int n_in,
                              void* d_out, int out_size, void* d_ws, size_t ws_size,
                              hipStream_t stream) {
    const float* x     = (const float*)d_in[0];
    const int*   q     = (const int*)  d_in[1];
    const float* scale = (const float*)d_in[2];
    const int*   zp    = (const int*)  d_in[3];
    const float* bias  = (const float*)d_in[4];
    float* out = (float*)d_out;

    hipMemsetAsync(out, 0, (size_t)out_size * sizeof(float), stream);

    const int blocks = (N_OUT / 32) * NCHUNK;  // 344 * 8 = 2752
    qlin_kernel<<<blocks, 256, 0, stream>>>(x, q, scale, zp, bias, out);
}